// Round 8
// baseline (589.414 us; speedup 1.0000x reference)
//
#include <hip/hip_runtime.h>

#define S_LEN 4096
#define BATCH 2
#define DIM 64
#define RAD 128
#define NPOS 257
#define KEXT 4416              // 4096 + 5*64 (rel rows padded)
#define QREL_STR 260
#define PSTR 72                // P LDS row stride in u16 (144B, 16B-aligned)
#define REPS 2

typedef short s16x8 __attribute__((ext_vector_type(8)));
typedef short s16x4 __attribute__((ext_vector_type(4)));
typedef float f32x4 __attribute__((ext_vector_type(4)));
typedef unsigned short u16;
typedef unsigned int u32;

__device__ __forceinline__ u16 f2bf(float f) {
  union { float f; u32 u; } v; v.f = f;
  u32 u = v.u;
  return (u16)((u + 0x7FFFu + ((u >> 16) & 1u)) >> 16);  // RNE
}

__global__ void prep_k(const float* __restrict__ K, const float* __restrict__ rel,
                       u16* __restrict__ Kb) {
  int b = blockIdx.y;
  int t = blockIdx.x * 4 + (threadIdx.x >> 6);
  int d = threadIdx.x & 63;
  float v = 0.f;
  if (t < S_LEN) v = K[((size_t)b * S_LEN + t) * DIM + d];
  else if (t - S_LEN < NPOS) v = rel[(size_t)(t - S_LEN) * DIM + d];
  Kb[((size_t)b * KEXT + t) * DIM + d] = f2bf(v);
}

__global__ void prep_v(const float* __restrict__ V, u16* __restrict__ Vt) {
  __shared__ float tile[64][65];
  int b = blockIdx.y;
  int t0 = blockIdx.x * 64;
  for (int i = threadIdx.x; i < 4096; i += 256) {
    int tl = i >> 6, d = i & 63;
    tile[tl][d] = V[((size_t)b * S_LEN + t0 + tl) * DIM + d];
  }
  __syncthreads();
  for (int i = threadIdx.x; i < 4096; i += 256) {
    int d = i >> 6, tl = i & 63;
    Vt[((size_t)b * DIM + d) * S_LEN + t0 + tl] = f2bf(tile[tl][d]);
  }
}

// PHASE-ABLATION PROBE, x2 repeat per arm so each arm outlasts the ~86us
// fillBuffer dispatches and shows up in the rocprof top-5 individually.
// MODE: 0=full  1=noQK(synthetic acc)  2=noPV(no V loads, no PV mfma)
//       3=noSM(junk P from qfrag, keeps V+PV)  4=QK+rel+store only.
// Rule #17: skipped values replaced by live substitutes, stores kept.
template <int MODE>
__launch_bounds__(256, 4)
__global__ void attn_main(const float* __restrict__ Q,
                          const u16* __restrict__ Kb,
                          const u16* __restrict__ Vt,
                          float* __restrict__ e0, float* __restrict__ e1,
                          float* __restrict__ z0, float* __restrict__ z1) {
  __shared__ float smem[16 * QREL_STR];
  __shared__ float smem2[2304];

  const int tid = threadIdx.x;
  const int lane = tid & 63;
  const int wid = tid >> 6;
  const int l15 = lane & 15, q4 = lane >> 4;
  const int bx = blockIdx.x;
  const int b = bx >> 8;
  const int s0 = (bx & 255) * 16;

  const u16* KbB = Kb + (size_t)b * KEXT * DIM;
  const u16* VtB = Vt + (size_t)b * DIM * S_LEN;
  u16* plds = (u16*)smem2;

  s16x8 qfrag[2];
  {
    const float* qp = Q + ((size_t)b * S_LEN + s0 + l15) * DIM + q4 * 8;
#pragma unroll
    for (int ks = 0; ks < 2; ++ks) {
      f32x4 a = *reinterpret_cast<const f32x4*>(qp + ks * 32);
      f32x4 c = *reinterpret_cast<const f32x4*>(qp + ks * 32 + 4);
      s16x8 f;
#pragma unroll
      for (int j = 0; j < 4; ++j) { f[j] = (short)f2bf(a[j]); f[4 + j] = (short)f2bf(c[j]); }
      qfrag[ks] = f;
    }
  }

  const int koff_lane = l15 * DIM + q4 * 8;

  for (int rep = 0; rep < REPS; ++rep) {
    float* energy = rep ? e1 : e0;
    float* Zout   = rep ? z1 : z0;
    __syncthreads();

    // ---- prologue: Q_rel via mfma(rel, q) ----
    for (int pt = wid; pt < 5; pt += 4) {
      f32x4 acc[4] = {};
      const u16* kp = KbB + (size_t)(S_LEN + pt * 64) * DIM + koff_lane;
#pragma unroll
      for (int ks = 0; ks < 2; ++ks)
#pragma unroll
        for (int nf = 0; nf < 4; ++nf) {
          s16x8 kf = *reinterpret_cast<const s16x8*>(kp + nf * 16 * DIM + ks * 32);
          acc[nf] = __builtin_amdgcn_mfma_f32_16x16x32_bf16(kf, qfrag[ks], acc[nf], 0, 0, 0);
        }
#pragma unroll
      for (int nf = 0; nf < 4; ++nf)
#pragma unroll
        for (int reg = 0; reg < 4; ++reg) {
          int p = pt * 64 + nf * 16 + q4 * 4 + reg;
          if (p < NPOS) smem[l15 * QREL_STR + p] = acc[nf][reg];
        }
    }
    __syncthreads();

    const float c8lo = smem[l15 * QREL_STR + 0] * 0.125f;
    const float c8hi = smem[l15 * QREL_STR + 256] * 0.125f;

    const int qglob = s0 + l15;
    const int qoff = l15 * QREL_STR + RAD;
    u16* pw = plds + wid * 16 * PSTR;
    float* erow = energy + ((size_t)b * S_LEN + qglob) * S_LEN;

    float mprev = -INFINITY, lsum = 0.f;
    f32x4 zacc[4] = {};

    for (int it = 0; it < 16; ++it) {
      const int t0 = wid * 1024 + it * 64;

      // ---- QK^T (or synthetic) ----
      f32x4 acc[4];
      if constexpr (MODE != 1) {
#pragma unroll
        for (int nf = 0; nf < 4; ++nf) acc[nf] = f32x4{0.f, 0.f, 0.f, 0.f};
        const u16* kp = KbB + (size_t)t0 * DIM + koff_lane;
#pragma unroll
        for (int ks = 0; ks < 2; ++ks)
#pragma unroll
          for (int nf = 0; nf < 4; ++nf) {
            s16x8 kf = *reinterpret_cast<const s16x8*>(kp + nf * 16 * DIM + ks * 32);
            acc[nf] = __builtin_amdgcn_mfma_f32_16x16x32_bf16(kf, qfrag[ks], acc[nf], 0, 0, 0);
          }
      } else {
#pragma unroll
        for (int nf = 0; nf < 4; ++nf)
#pragma unroll
          for (int reg = 0; reg < 4; ++reg)
            acc[nf][reg] = (float)((lane + nf * 5 + reg * 3 + it) & 15) * 0.25f - 2.0f;
      }

      // ---- V fragments ----
      s16x8 vf[2][4];
      if constexpr (MODE == 0 || MODE == 1 || MODE == 3) {
#pragma unroll
        for (int ks = 0; ks < 2; ++ks)
#pragma unroll
          for (int dn = 0; dn < 4; ++dn)
            vf[ks][dn] = *reinterpret_cast<const s16x8*>(
                VtB + (size_t)(dn * 16 + l15) * S_LEN + t0 + ks * 32 + q4 * 8);
      }

      // ---- rel shift + scale + lane max ----
      float mloc = -INFINITY;
      if (t0 >= s0 + 143) {
#pragma unroll
        for (int nf = 0; nf < 4; ++nf)
#pragma unroll
          for (int reg = 0; reg < 4; ++reg) {
            float e = fmaf(acc[nf][reg], 0.125f, c8hi);
            acc[nf][reg] = e; mloc = fmaxf(mloc, e);
          }
      } else if (t0 <= s0 - 191) {
#pragma unroll
        for (int nf = 0; nf < 4; ++nf)
#pragma unroll
          for (int reg = 0; reg < 4; ++reg) {
            float e = fmaf(acc[nf][reg], 0.125f, c8lo);
            acc[nf][reg] = e; mloc = fmaxf(mloc, e);
          }
      } else {
#pragma unroll
        for (int nf = 0; nf < 4; ++nf) {
          const int tb = t0 + nf * 16 + q4 * 4;
#pragma unroll
          for (int reg = 0; reg < 4; ++reg) {
            int p = tb + reg - qglob;
            p = (p < -RAD) ? -RAD : (p > RAD ? RAD : p);
            float e = (acc[nf][reg] + smem[qoff + p]) * 0.125f;
            acc[nf][reg] = e; mloc = fmaxf(mloc, e);
          }
        }
      }

      // ---- energy store (all modes) ----
#pragma unroll
      for (int nf = 0; nf < 4; ++nf)
        __builtin_nontemporal_store(
            acc[nf], reinterpret_cast<f32x4*>(erow + t0 + nf * 16 + q4 * 4));

      // ---- softmax + P pack (modes 0,1,2) ----
      if constexpr (MODE <= 2) {
        if (__all(mloc <= mprev)) {
        } else {
          mloc = fmaxf(mloc, __shfl_xor(mloc, 16));
          mloc = fmaxf(mloc, __shfl_xor(mloc, 32));
          const float mn = fmaxf(mprev, mloc);
          const float alpha = __expf(mprev - mn);
          mprev = mn;
          lsum *= alpha;
#pragma unroll
          for (int dn = 0; dn < 4; ++dn) zacc[dn] *= alpha;
        }
        float rs = 0.f;
#pragma unroll
        for (int nf = 0; nf < 4; ++nf) {
          float p0 = __expf(acc[nf][0] - mprev);
          float p1 = __expf(acc[nf][1] - mprev);
          float p2 = __expf(acc[nf][2] - mprev);
          float p3 = __expf(acc[nf][3] - mprev);
          rs += (p0 + p1) + (p2 + p3);
          union { u32 w[2]; s16x4 v; } pk;
          asm("v_cvt_pk_bf16_f32 %0, %1, %2" : "=v"(pk.w[0]) : "v"(p0), "v"(p1));
          asm("v_cvt_pk_bf16_f32 %0, %1, %2" : "=v"(pk.w[1]) : "v"(p2), "v"(p3));
          asm volatile("" ::"v"(pk.w[0]), "v"(pk.w[1]));  // keep live even if LDS store DCE'd
          *reinterpret_cast<s16x4*>(pw + l15 * PSTR + nf * 16 + q4 * 4) = pk.v;
        }
        rs += __shfl_xor(rs, 16);
        rs += __shfl_xor(rs, 32);
        lsum += rs;
      }

      // ---- PV ----
      if constexpr (MODE == 0 || MODE == 1) {
#pragma unroll
        for (int ks = 0; ks < 2; ++ks) {
          s16x8 pf = *reinterpret_cast<const s16x8*>(pw + l15 * PSTR + ks * 32 + q4 * 8);
#pragma unroll
          for (int dn = 0; dn < 4; ++dn)
            zacc[dn] = __builtin_amdgcn_mfma_f32_16x16x32_bf16(vf[ks][dn], pf, zacc[dn], 0, 0, 0);
        }
      } else if constexpr (MODE == 3) {
#pragma unroll
        for (int ks = 0; ks < 2; ++ks) {
          s16x8 pf = qfrag[ks];  // junk values, keeps V+PV pipe cost
#pragma unroll
          for (int dn = 0; dn < 4; ++dn)
            zacc[dn] = __builtin_amdgcn_mfma_f32_16x16x32_bf16(vf[ks][dn], pf, zacc[dn], 0, 0, 0);
        }
      }
    }

    if constexpr (MODE >= 3) { mprev = 0.f; lsum = 1.f; }

    // ---- cross-wave combine ----
    __syncthreads();
#pragma unroll
    for (int dn = 0; dn < 4; ++dn)
      *reinterpret_cast<f32x4*>(&smem[(wid * 16 + l15) * 64 + dn * 16 + q4 * 4]) = zacc[dn];
    if (q4 == 0) {
      smem2[wid * 16 + l15] = mprev;
      smem2[64 + wid * 16 + l15] = lsum;
    }
    __syncthreads();
    {
      const int r0 = tid >> 6, d = tid & 63;
#pragma unroll
      for (int rr = 0; rr < 4; ++rr) {
        const int r = rr * 4 + r0;
        float mf = -INFINITY;
#pragma unroll
        for (int w = 0; w < 4; ++w) mf = fmaxf(mf, smem2[w * 16 + r]);
        float lf = 0.f, z = 0.f;
#pragma unroll
        for (int w = 0; w < 4; ++w) {
          const float sc = __expf(smem2[w * 16 + r] - mf);
          lf += smem2[64 + w * 16 + r] * sc;
          z  += smem[(w * 16 + r) * 64 + d] * sc;
        }
        Zout[((size_t)b * S_LEN + s0 + r) * DIM + d] = z / lf;
      }
    }
  }
}

extern "C" void kernel_launch(void* const* d_in, const int* in_sizes, int n_in,
                              void* d_out, int out_size, void* d_ws, size_t ws_size,
                              hipStream_t stream) {
  const float* Q   = (const float*)d_in[0];
  const float* K   = (const float*)d_in[1];
  const float* V   = (const float*)d_in[2];
  const float* rel = (const float*)d_in[3];

  u16* Kb = (u16*)d_ws;                                   // [B][KEXT][64] bf16
  u16* Vt = Kb + (size_t)BATCH * KEXT * DIM;              // [B][64][S] bf16
  float* wsZ = (float*)(Vt + (size_t)BATCH * DIM * S_LEN);   // 2 MB
  float* wsE = wsZ + (size_t)BATCH * S_LEN * DIM;            // 134 MB (proven available in R6)

  float* energy = (float*)d_out;
  float* Zout   = energy + (size_t)BATCH * S_LEN * S_LEN;

  prep_k<<<dim3(KEXT / 4, BATCH), 256, 0, stream>>>(K, rel, Kb);
  prep_v<<<dim3(S_LEN / 64, BATCH), 256, 0, stream>>>(V, Vt);

  const dim3 g(BATCH * (S_LEN / 16));
  attn_main<1><<<g, 256, 0, stream>>>(Q, Kb, Vt, wsE, wsE, wsZ, wsZ);  // B noQK
  attn_main<2><<<g, 256, 0, stream>>>(Q, Kb, Vt, wsE, wsE, wsZ, wsZ);  // C noPV
  attn_main<3><<<g, 256, 0, stream>>>(Q, Kb, Vt, wsE, wsE, wsZ, wsZ);  // D noSM
  attn_main<4><<<g, 256, 0, stream>>>(Q, Kb, Vt, wsE, wsE, wsZ, wsZ);  // E QKonly
  attn_main<0><<<g, 256, 0, stream>>>(Q, Kb, Vt, wsE, energy, wsZ, Zout);  // A full, real out
}

// Round 9
// 513.581 us; speedup vs baseline: 1.1477x; 1.1477x over previous
//
#include <hip/hip_runtime.h>

#define S_LEN 4096
#define BATCH 2
#define DIM 64
#define RAD 128
#define NPOS 257
#define KEXT 4416              // 4096 + 5*64 (rel rows padded)
#define QREL_STR 260
#define PSTR 72                // P LDS row stride in u16 (144B, 16B-aligned)
#define PROBE_REPS 6

typedef short s16x8 __attribute__((ext_vector_type(8)));
typedef short s16x4 __attribute__((ext_vector_type(4)));
typedef float f32x4 __attribute__((ext_vector_type(4)));
typedef unsigned short u16;
typedef unsigned int u32;

__device__ __forceinline__ u16 f2bf(float f) {
  union { float f; u32 u; } v; v.f = f;
  u32 u = v.u;
  return (u16)((u + 0x7FFFu + ((u >> 16) & 1u)) >> 16);  // RNE
}

__global__ void prep_k(const float* __restrict__ K, const float* __restrict__ rel,
                       u16* __restrict__ Kb) {
  int b = blockIdx.y;
  int t = blockIdx.x * 4 + (threadIdx.x >> 6);
  int d = threadIdx.x & 63;
  float v = 0.f;
  if (t < S_LEN) v = K[((size_t)b * S_LEN + t) * DIM + d];
  else if (t - S_LEN < NPOS) v = rel[(size_t)(t - S_LEN) * DIM + d];
  Kb[((size_t)b * KEXT + t) * DIM + d] = f2bf(v);
}

__global__ void prep_v(const float* __restrict__ V, u16* __restrict__ Vt) {
  __shared__ float tile[64][65];
  int b = blockIdx.y;
  int t0 = blockIdx.x * 64;
  for (int i = threadIdx.x; i < 4096; i += 256) {
    int tl = i >> 6, d = i & 63;
    tile[tl][d] = V[((size_t)b * S_LEN + t0 + tl) * DIM + d];
  }
  __syncthreads();
  for (int i = threadIdx.x; i < 4096; i += 256) {
    int d = i >> 6, tl = i & 63;
    Vt[((size_t)b * DIM + d) * S_LEN + t0 + tl] = f2bf(tile[tl][d]);
  }
}

// STORE-ONLY probe: R7's exact energy-store pattern (same grid, same addresses,
// same nt f32x4 instructions) fed by cheap synthetic register data. No loads,
// no MFMA, no LDS. x PROBE_REPS.
__launch_bounds__(256, 4)
__global__ void store_probe(float* __restrict__ wsE) {
  const int tid = threadIdx.x;
  const int lane = tid & 63;
  const int wid = tid >> 6;
  const int l15 = lane & 15, q4 = lane >> 4;
  const int bx = blockIdx.x;
  const int b = bx >> 8;
  const int s0 = (bx & 255) * 16;
  float* erow = wsE + ((size_t)b * S_LEN + s0 + l15) * S_LEN;
  float x = (float)(tid * 3 + (bx & 63)) * 0.00390625f;
  for (int rep = 0; rep < PROBE_REPS; ++rep) {
    for (int it = 0; it < 16; ++it) {
      const int t0 = wid * 1024 + it * 64;
#pragma unroll
      for (int nf = 0; nf < 4; ++nf) {
        f32x4 v;
#pragma unroll
        for (int r = 0; r < 4; ++r) { x = fmaf(x, 0.5f, 1.25f); v[r] = x; }
        __builtin_nontemporal_store(v, reinterpret_cast<f32x4*>(erow + t0 + nf * 16 + q4 * 4));
      }
    }
  }
}

// MODE 0 = real kernel (1 rep, energy -> d_out).
// MODE 1 = COMPUTE-ONLY probe: identical except energy stores removed
//          (acc still feeds softmax->P->Z so nothing is dead; asm sink for
//          belt-and-braces), x PROBE_REPS with opaque per-rep pointer offset
//          so loads can't be CSE'd across reps.
template <int MODE>
__launch_bounds__(256, 4)
__global__ void attn_main(const float* __restrict__ Q,
                          const u16* __restrict__ Kb,
                          const u16* __restrict__ Vt,
                          float* __restrict__ energy,
                          float* __restrict__ Zout) {
  __shared__ float smem[16 * QREL_STR];
  __shared__ float smem2[2304];

  const int tid = threadIdx.x;
  const int lane = tid & 63;
  const int wid = tid >> 6;
  const int l15 = lane & 15, q4 = lane >> 4;
  const int bx = blockIdx.x;
  const int b = bx >> 8;
  const int s0 = (bx & 255) * 16;

  const u16* KbB = Kb + (size_t)b * KEXT * DIM;
  const u16* VtB = Vt + (size_t)b * DIM * S_LEN;
  u16* plds = (u16*)smem2;

  s16x8 qfrag[2];
  {
    const float* qp = Q + ((size_t)b * S_LEN + s0 + l15) * DIM + q4 * 8;
#pragma unroll
    for (int ks = 0; ks < 2; ++ks) {
      f32x4 a = *reinterpret_cast<const f32x4*>(qp + ks * 32);
      f32x4 c = *reinterpret_cast<const f32x4*>(qp + ks * 32 + 4);
      s16x8 f;
#pragma unroll
      for (int j = 0; j < 4; ++j) { f[j] = (short)f2bf(a[j]); f[4 + j] = (short)f2bf(c[j]); }
      qfrag[ks] = f;
    }
  }

  const int koff_lane = l15 * DIM + q4 * 8;

  for (int pt = wid; pt < 5; pt += 4) {
    f32x4 acc[4] = {};
    const u16* kp = KbB + (size_t)(S_LEN + pt * 64) * DIM + koff_lane;
#pragma unroll
    for (int ks = 0; ks < 2; ++ks)
#pragma unroll
      for (int nf = 0; nf < 4; ++nf) {
        s16x8 kf = *reinterpret_cast<const s16x8*>(kp + nf * 16 * DIM + ks * 32);
        acc[nf] = __builtin_amdgcn_mfma_f32_16x16x32_bf16(kf, qfrag[ks], acc[nf], 0, 0, 0);
      }
#pragma unroll
    for (int nf = 0; nf < 4; ++nf)
#pragma unroll
      for (int reg = 0; reg < 4; ++reg) {
        int p = pt * 64 + nf * 16 + q4 * 4 + reg;
        if (p < NPOS) smem[l15 * QREL_STR + p] = acc[nf][reg];
      }
  }
  __syncthreads();

  const float c8lo = smem[l15 * QREL_STR + 0] * 0.125f;
  const float c8hi = smem[l15 * QREL_STR + 256] * 0.125f;

  const int qglob = s0 + l15;
  const int qoff = l15 * QREL_STR + RAD;
  u16* pw = plds + wid * 16 * PSTR;
  float* erow = energy + ((size_t)b * S_LEN + qglob) * S_LEN;

  float mprev = -INFINITY, lsum = 0.f;
  f32x4 zacc[4] = {};

  const int nrep = (MODE == 1) ? PROBE_REPS : 1;
  for (int rep = 0; rep < nrep; ++rep) {
    int zoff = 0;
    if constexpr (MODE == 1)
      asm("v_and_b32 %0, 0, %1" : "=v"(zoff) : "v"(rep));  // opaque 0, rep-dependent
    const u16* KbR = KbB + zoff;
    const u16* VtR = VtB + zoff;

    for (int it = 0; it < 16; ++it) {
      const int t0 = wid * 1024 + it * 64;

      f32x4 acc[4] = {};
      const u16* kp = KbR + (size_t)t0 * DIM + koff_lane;
#pragma unroll
      for (int ks = 0; ks < 2; ++ks)
#pragma unroll
        for (int nf = 0; nf < 4; ++nf) {
          s16x8 kf = *reinterpret_cast<const s16x8*>(kp + nf * 16 * DIM + ks * 32);
          acc[nf] = __builtin_amdgcn_mfma_f32_16x16x32_bf16(kf, qfrag[ks], acc[nf], 0, 0, 0);
        }

      s16x8 vf[2][4];
#pragma unroll
      for (int ks = 0; ks < 2; ++ks)
#pragma unroll
        for (int dn = 0; dn < 4; ++dn)
          vf[ks][dn] = *reinterpret_cast<const s16x8*>(
              VtR + (size_t)(dn * 16 + l15) * S_LEN + t0 + ks * 32 + q4 * 8);

      float mloc = -INFINITY;
      if (t0 >= s0 + 143) {
#pragma unroll
        for (int nf = 0; nf < 4; ++nf)
#pragma unroll
          for (int reg = 0; reg < 4; ++reg) {
            float e = fmaf(acc[nf][reg], 0.125f, c8hi);
            acc[nf][reg] = e; mloc = fmaxf(mloc, e);
          }
      } else if (t0 <= s0 - 191) {
#pragma unroll
        for (int nf = 0; nf < 4; ++nf)
#pragma unroll
          for (int reg = 0; reg < 4; ++reg) {
            float e = fmaf(acc[nf][reg], 0.125f, c8lo);
            acc[nf][reg] = e; mloc = fmaxf(mloc, e);
          }
      } else {
#pragma unroll
        for (int nf = 0; nf < 4; ++nf) {
          const int tb = t0 + nf * 16 + q4 * 4;
#pragma unroll
          for (int reg = 0; reg < 4; ++reg) {
            int p = tb + reg - qglob;
            p = (p < -RAD) ? -RAD : (p > RAD ? RAD : p);
            float e = (acc[nf][reg] + smem[qoff + p]) * 0.125f;
            acc[nf][reg] = e; mloc = fmaxf(mloc, e);
          }
        }
      }

      if constexpr (MODE == 0) {
#pragma unroll
        for (int nf = 0; nf < 4; ++nf)
          __builtin_nontemporal_store(
              acc[nf], reinterpret_cast<f32x4*>(erow + t0 + nf * 16 + q4 * 4));
      } else {
#pragma unroll
        for (int nf = 0; nf < 4; ++nf)
          asm volatile("" ::"v"(acc[nf][0]), "v"(acc[nf][1]), "v"(acc[nf][2]), "v"(acc[nf][3]));
      }

      if (__all(mloc <= mprev)) {
      } else {
        mloc = fmaxf(mloc, __shfl_xor(mloc, 16));
        mloc = fmaxf(mloc, __shfl_xor(mloc, 32));
        const float mn = fmaxf(mprev, mloc);
        const float alpha = __expf(mprev - mn);
        mprev = mn;
        lsum *= alpha;
#pragma unroll
        for (int dn = 0; dn < 4; ++dn) zacc[dn] *= alpha;
      }

      float rs = 0.f;
#pragma unroll
      for (int nf = 0; nf < 4; ++nf) {
        float p0 = __expf(acc[nf][0] - mprev);
        float p1 = __expf(acc[nf][1] - mprev);
        float p2 = __expf(acc[nf][2] - mprev);
        float p3 = __expf(acc[nf][3] - mprev);
        rs += (p0 + p1) + (p2 + p3);
        union { u32 w[2]; s16x4 v; } pk;
        asm("v_cvt_pk_bf16_f32 %0, %1, %2" : "=v"(pk.w[0]) : "v"(p0), "v"(p1));
        asm("v_cvt_pk_bf16_f32 %0, %1, %2" : "=v"(pk.w[1]) : "v"(p2), "v"(p3));
        *reinterpret_cast<s16x4*>(pw + l15 * PSTR + nf * 16 + q4 * 4) = pk.v;
      }
      rs += __shfl_xor(rs, 16);
      rs += __shfl_xor(rs, 32);
      lsum += rs;

#pragma unroll
      for (int ks = 0; ks < 2; ++ks) {
        s16x8 pf = *reinterpret_cast<const s16x8*>(pw + l15 * PSTR + ks * 32 + q4 * 8);
#pragma unroll
        for (int dn = 0; dn < 4; ++dn)
          zacc[dn] = __builtin_amdgcn_mfma_f32_16x16x32_bf16(vf[ks][dn], pf, zacc[dn], 0, 0, 0);
      }
    }
  }

  __syncthreads();
#pragma unroll
  for (int dn = 0; dn < 4; ++dn)
    *reinterpret_cast<f32x4*>(&smem[(wid * 16 + l15) * 64 + dn * 16 + q4 * 4]) = zacc[dn];
  if (q4 == 0) {
    smem2[wid * 16 + l15] = mprev;
    smem2[64 + wid * 16 + l15] = lsum;
  }
  __syncthreads();
  {
    const int r0 = tid >> 6, d = tid & 63;
#pragma unroll
    for (int rr = 0; rr < 4; ++rr) {
      const int r = rr * 4 + r0;
      float mf = -INFINITY;
#pragma unroll
      for (int w = 0; w < 4; ++w) mf = fmaxf(mf, smem2[w * 16 + r]);
      float lf = 0.f, z = 0.f;
#pragma unroll
      for (int w = 0; w < 4; ++w) {
        const float sc = __expf(smem2[w * 16 + r] - mf);
        lf += smem2[64 + w * 16 + r] * sc;
        z  += smem[(w * 16 + r) * 64 + d] * sc;
      }
      Zout[((size_t)b * S_LEN + s0 + r) * DIM + d] = z / lf;
    }
  }
}

extern "C" void kernel_launch(void* const* d_in, const int* in_sizes, int n_in,
                              void* d_out, int out_size, void* d_ws, size_t ws_size,
                              hipStream_t stream) {
  const float* Q   = (const float*)d_in[0];
  const float* K   = (const float*)d_in[1];
  const float* V   = (const float*)d_in[2];
  const float* rel = (const float*)d_in[3];

  u16* Kb = (u16*)d_ws;                                      // [B][KEXT][64] bf16
  u16* Vt = Kb + (size_t)BATCH * KEXT * DIM;                 // [B][64][S] bf16
  float* wsZ = (float*)(Vt + (size_t)BATCH * DIM * S_LEN);   // 2 MB scratch Z
  float* wsE = wsZ + (size_t)BATCH * S_LEN * DIM;            // 134 MB scratch energy

  float* energy = (float*)d_out;
  float* Zout   = energy + (size_t)BATCH * S_LEN * S_LEN;

  prep_k<<<dim3(KEXT / 4, BATCH), 256, 0, stream>>>(K, rel, Kb);
  prep_v<<<dim3(S_LEN / 64, BATCH), 256, 0, stream>>>(V, Vt);

  const dim3 g(BATCH * (S_LEN / 16));
  // Probe 1: compute-only (no energy stores), x6 reps
  attn_main<1><<<g, 256, 0, stream>>>(Q, Kb, Vt, wsZ, wsZ);
  // Probe 2: store-only (exact R7 store pattern, synthetic data), x6 reps
  store_probe<<<g, 256, 0, stream>>>(wsE);
  // Real kernel (unchanged R7), writes d_out
  attn_main<0><<<g, 256, 0, stream>>>(Q, Kb, Vt, energy, Zout);
}

// Round 11
// 81.844 us; speedup vs baseline: 7.2017x; 6.2751x over previous
//
#include <hip/hip_runtime.h>

#define S_LEN 4096
#define BATCH 2
#define DIM 64
#define RAD 128
#define NPOS 257
#define KEXT 4416              // 4096 + 5*64 (rel rows padded)
#define QREL_STR 260
#define PSTR 72                // P LDS row stride in u16 (144B, 16B-aligned)

typedef short s16x8 __attribute__((ext_vector_type(8)));
typedef short s16x4 __attribute__((ext_vector_type(4)));
typedef float f32x4 __attribute__((ext_vector_type(4)));
typedef unsigned short u16;
typedef unsigned int u32;

__device__ __forceinline__ u16 f2bf(float f) {
  union { float f; u32 u; } v; v.f = f;
  u32 u = v.u;
  return (u16)((u + 0x7FFFu + ((u >> 16) & 1u)) >> 16);  // RNE
}

// Kb_ext[b][t][d]: t<4096 -> bf16(K); 4096<=t<4353 -> bf16(rel[t-4096]); else 0
__global__ void prep_k(const float* __restrict__ K, const float* __restrict__ rel,
                       u16* __restrict__ Kb) {
  int b = blockIdx.y;
  int t = blockIdx.x * 4 + (threadIdx.x >> 6);
  int d = threadIdx.x & 63;
  float v = 0.f;
  if (t < S_LEN) v = K[((size_t)b * S_LEN + t) * DIM + d];
  else if (t - S_LEN < NPOS) v = rel[(size_t)(t - S_LEN) * DIM + d];
  Kb[((size_t)b * KEXT + t) * DIM + d] = f2bf(v);
}

// Vt[b][d][t] = bf16(V[b][t][d])
__global__ void prep_v(const float* __restrict__ V, u16* __restrict__ Vt) {
  __shared__ float tile[64][65];
  int b = blockIdx.y;
  int t0 = blockIdx.x * 64;
  for (int i = threadIdx.x; i < 4096; i += 256) {
    int tl = i >> 6, d = i & 63;
    tile[tl][d] = V[((size_t)b * S_LEN + t0 + tl) * DIM + d];
  }
  __syncthreads();
  for (int i = threadIdx.x; i < 4096; i += 256) {
    int d = i >> 6, tl = i & 63;
    Vt[((size_t)b * DIM + d) * S_LEN + t0 + tl] = f2bf(tile[tl][d]);
  }
}

// 16 q-rows per block, 8 waves (512 thr); wave w owns cols [w*512,(w+1)*512).
// 2x the resident waves of R7/R9 (4 waves/SIMD) to hide the per-tile
// dependent-chain latency (R9 ablation: compute floor 60us at 2 waves/SIMD,
// no pipe saturated). Loop body identical to R7 (proven); 8-wave epilogue
// identical to R1-R5 (proven). Barrier-free main loop.
// Swapped-operand MFMAs keep q == l15 lane-local:
//   QK^T: mfma(kf, qf) -> D[t=q4*4+reg][q=l15]
//   PV:   mfma(vf, pf) -> D[d=dn*16+q4*4+reg][q=l15]
__launch_bounds__(512, 4)
__global__ void attn_main(const float* __restrict__ Q,
                          const u16* __restrict__ Kb,
                          const u16* __restrict__ Vt,
                          float* __restrict__ energy,
                          float* __restrict__ Zout) {
  __shared__ float uni[8448];          // phase1: qrel[16][260]; phase2: Zbuf[8][16][64]+m[128]+l[128]
  __shared__ u16 plds[8 * 16 * PSTR];  // 18432 B

  const int tid = threadIdx.x;
  const int lane = tid & 63;
  const int wid = tid >> 6;            // 0..7
  const int l15 = lane & 15, q4 = lane >> 4;
  const int bx = blockIdx.x;
  const int b = bx >> 8;
  const int s0 = (bx & 255) * 16;

  const u16* KbB = Kb + (size_t)b * KEXT * DIM;
  const u16* VtB = Vt + (size_t)b * DIM * S_LEN;

  // ---- Q B-fragments (row s0+l15) ----
  s16x8 qfrag[2];
  {
    const float* qp = Q + ((size_t)b * S_LEN + s0 + l15) * DIM + q4 * 8;
#pragma unroll
    for (int ks = 0; ks < 2; ++ks) {
      f32x4 a = *reinterpret_cast<const f32x4*>(qp + ks * 32);
      f32x4 c = *reinterpret_cast<const f32x4*>(qp + ks * 32 + 4);
      s16x8 f;
#pragma unroll
      for (int j = 0; j < 4; ++j) { f[j] = (short)f2bf(a[j]); f[4 + j] = (short)f2bf(c[j]); }
      qfrag[ks] = f;
    }
  }

  const int koff_lane = l15 * DIM + q4 * 8;

  // ---- prologue: Q_rel[p][q] via mfma(rel, q); waves 0..4 each one chunk ----
  for (int pt = wid; pt < 5; pt += 8) {
    f32x4 acc[4] = {};
    const u16* kp = KbB + (size_t)(S_LEN + pt * 64) * DIM + koff_lane;
#pragma unroll
    for (int ks = 0; ks < 2; ++ks)
#pragma unroll
      for (int nf = 0; nf < 4; ++nf) {
        s16x8 kf = *reinterpret_cast<const s16x8*>(kp + nf * 16 * DIM + ks * 32);
        acc[nf] = __builtin_amdgcn_mfma_f32_16x16x32_bf16(kf, qfrag[ks], acc[nf], 0, 0, 0);
      }
#pragma unroll
    for (int nf = 0; nf < 4; ++nf)
#pragma unroll
      for (int reg = 0; reg < 4; ++reg) {
        int p = pt * 64 + nf * 16 + q4 * 4 + reg;
        if (p < NPOS) uni[l15 * QREL_STR + p] = acc[nf][reg];
      }
  }
  __syncthreads();

  // per-row clamped-rel constants, pre-scaled by 1/8
  const float c8lo = uni[l15 * QREL_STR + 0] * 0.125f;
  const float c8hi = uni[l15 * QREL_STR + 256] * 0.125f;

  // ---- main loop: 8 t-tiles of 64 per wave, barrier-free ----
  const int qglob = s0 + l15;
  const int qoff = l15 * QREL_STR + RAD;
  u16* pw = plds + wid * 16 * PSTR;
  float* erow = energy + ((size_t)b * S_LEN + qglob) * S_LEN;

  float mprev = -INFINITY, lsum = 0.f;
  f32x4 zacc[4] = {};

  for (int it = 0; it < 8; ++it) {
    const int t0 = wid * 512 + it * 64;

    // QK^T
    f32x4 acc[4] = {};
    const u16* kp = KbB + (size_t)t0 * DIM + koff_lane;
#pragma unroll
    for (int ks = 0; ks < 2; ++ks)
#pragma unroll
      for (int nf = 0; nf < 4; ++nf) {
        s16x8 kf = *reinterpret_cast<const s16x8*>(kp + nf * 16 * DIM + ks * 32);
        acc[nf] = __builtin_amdgcn_mfma_f32_16x16x32_bf16(kf, qfrag[ks], acc[nf], 0, 0, 0);
      }

    // V fragments issued early; latency hides under softmax
    s16x8 vf[2][4];
#pragma unroll
    for (int ks = 0; ks < 2; ++ks)
#pragma unroll
      for (int dn = 0; dn < 4; ++dn)
        vf[ks][dn] = *reinterpret_cast<const s16x8*>(
            VtB + (size_t)(dn * 16 + l15) * S_LEN + t0 + ks * 32 + q4 * 8);

    // rel shift + scale (band-split: fma for out-of-band tiles), lane max
    float mloc = -INFINITY;
    if (t0 >= s0 + 143) {
#pragma unroll
      for (int nf = 0; nf < 4; ++nf)
#pragma unroll
        for (int reg = 0; reg < 4; ++reg) {
          float e = fmaf(acc[nf][reg], 0.125f, c8hi);
          acc[nf][reg] = e;
          mloc = fmaxf(mloc, e);
        }
    } else if (t0 <= s0 - 191) {
#pragma unroll
      for (int nf = 0; nf < 4; ++nf)
#pragma unroll
        for (int reg = 0; reg < 4; ++reg) {
          float e = fmaf(acc[nf][reg], 0.125f, c8lo);
          acc[nf][reg] = e;
          mloc = fmaxf(mloc, e);
        }
    } else {
#pragma unroll
      for (int nf = 0; nf < 4; ++nf) {
        const int tb = t0 + nf * 16 + q4 * 4;
#pragma unroll
        for (int reg = 0; reg < 4; ++reg) {
          int p = tb + reg - qglob;
          p = (p < -RAD) ? -RAD : (p > RAD ? RAD : p);
          float e = (acc[nf][reg] + uni[qoff + p]) * 0.125f;
          acc[nf][reg] = e;
          mloc = fmaxf(mloc, e);
        }
      }
    }

    // energy store, direct from regs (R6/R9: stores are not the bottleneck)
#pragma unroll
    for (int nf = 0; nf < 4; ++nf)
      __builtin_nontemporal_store(
          acc[nf], reinterpret_cast<f32x4*>(erow + t0 + nf * 16 + q4 * 4));

    // online softmax; skip rescale when max didn't grow
    if (__all(mloc <= mprev)) {
      // keep mprev; zacc/lsum unchanged
    } else {
      mloc = fmaxf(mloc, __shfl_xor(mloc, 16));
      mloc = fmaxf(mloc, __shfl_xor(mloc, 32));
      const float mn = fmaxf(mprev, mloc);
      const float alpha = __expf(mprev - mn);
      mprev = mn;
      lsum *= alpha;
#pragma unroll
      for (int dn = 0; dn < 4; ++dn) zacc[dn] *= alpha;
    }

    float rs = 0.f;
#pragma unroll
    for (int nf = 0; nf < 4; ++nf) {
      float p0 = __expf(acc[nf][0] - mprev);
      float p1 = __expf(acc[nf][1] - mprev);
      float p2 = __expf(acc[nf][2] - mprev);
      float p3 = __expf(acc[nf][3] - mprev);
      rs += (p0 + p1) + (p2 + p3);
      union { u32 w[2]; s16x4 v; } pk;
      asm("v_cvt_pk_bf16_f32 %0, %1, %2" : "=v"(pk.w[0]) : "v"(p0), "v"(p1));
      asm("v_cvt_pk_bf16_f32 %0, %1, %2" : "=v"(pk.w[1]) : "v"(p2), "v"(p3));
      *reinterpret_cast<s16x4*>(pw + l15 * PSTR + nf * 16 + q4 * 4) = pk.v;
    }
    rs += __shfl_xor(rs, 16);
    rs += __shfl_xor(rs, 32);
    lsum += rs;

    // PV: mfma(vf, pf) -> zacc[dn] holds Z[d=dn*16+q4*4+reg][q=l15]
#pragma unroll
    for (int ks = 0; ks < 2; ++ks) {
      s16x8 pf = *reinterpret_cast<const s16x8*>(pw + l15 * PSTR + ks * 32 + q4 * 8);
#pragma unroll
      for (int dn = 0; dn < 4; ++dn)
        zacc[dn] = __builtin_amdgcn_mfma_f32_16x16x32_bf16(vf[ks][dn], pf, zacc[dn], 0, 0, 0);
    }
  }

  // ---- cross-wave combine (reuse uni: Zbuf[0..8192), m[8192..8320), l[8320..8448)) ----
  __syncthreads();
#pragma unroll
  for (int dn = 0; dn < 4; ++dn)
    *reinterpret_cast<f32x4*>(&uni[(wid * 16 + l15) * 64 + dn * 16 + q4 * 4]) = zacc[dn];
  if (q4 == 0) {
    uni[8192 + wid * 16 + l15] = mprev;
    uni[8320 + wid * 16 + l15] = lsum;
  }
  __syncthreads();

  {
    const int r0 = tid >> 6, d = tid & 63;
#pragma unroll
    for (int rr = 0; rr < 2; ++rr) {
      const int r = rr * 8 + r0;
      float mf = -INFINITY;
#pragma unroll
      for (int w = 0; w < 8; ++w) mf = fmaxf(mf, uni[8192 + w * 16 + r]);
      float lf = 0.f, z = 0.f;
#pragma unroll
      for (int w = 0; w < 8; ++w) {
        const float sc = __expf(uni[8192 + w * 16 + r] - mf);
        lf += uni[8320 + w * 16 + r] * sc;
        z  += uni[(w * 16 + r) * 64 + d] * sc;
      }
      Zout[((size_t)b * S_LEN + s0 + r) * DIM + d] = z / lf;
    }
  }
}

extern "C" void kernel_launch(void* const* d_in, const int* in_sizes, int n_in,
                              void* d_out, int out_size, void* d_ws, size_t ws_size,
                              hipStream_t stream) {
  const float* Q   = (const float*)d_in[0];
  const float* K   = (const float*)d_in[1];
  const float* V   = (const float*)d_in[2];
  const float* rel = (const float*)d_in[3];
  // d_in[4] = segment_ids (unused, segmented=False)

  u16* Kb = (u16*)d_ws;                                   // [B][KEXT][64] bf16
  u16* Vt = Kb + (size_t)BATCH * KEXT * DIM;              // [B][64][S] bf16

  float* energy = (float*)d_out;                          // [B][S][S]
  float* Zout   = energy + (size_t)BATCH * S_LEN * S_LEN; // [B][S][64]

  prep_k<<<dim3(KEXT / 4, BATCH), 256, 0, stream>>>(K, rel, Kb);
  prep_v<<<dim3(S_LEN / 64, BATCH), 256, 0, stream>>>(V, Vt);
  attn_main<<<dim3(BATCH * (S_LEN / 16)), 512, 0, stream>>>(Q, Kb, Vt, energy, Zout);
}

// Round 12
// 52.824 us; speedup vs baseline: 11.1581x; 1.5494x over previous
//
#include <hip/hip_runtime.h>

#define S_LEN 4096
#define BATCH 2
#define DIM 64
#define RAD 128
#define NPOS 257
#define KEXT 4416              // 4096 + 5*64 (rel rows padded); KEXT/16 = 276 tiles
#define NKT 276                // K fragment tiles per batch
#define QREL_STR 260
#define PSTR 72                // P LDS row stride in u16 (144B, 16B-aligned)

typedef short s16x8 __attribute__((ext_vector_type(8)));
typedef short s16x4 __attribute__((ext_vector_type(4)));
typedef float f32x4 __attribute__((ext_vector_type(4)));
typedef unsigned short u16;
typedef unsigned int u32;

__device__ __forceinline__ u16 f2bf(float f) {
  union { float f; u32 u; } v; v.f = f;
  u32 u = v.u;
  return (u16)((u + 0x7FFFu + ((u >> 16) & 1u)) >> 16);  // RNE
}

// KF[b][Ti][ks][lane][j]: the exact s16x8 lane `lane` needs for the QK MFMA
// fragment of K-tile Ti, k-slice ks. Lane's 16B is CONTIGUOUS; a wave's
// fragment load is one 1KB coalesced burst (vs 16 scattered 64B segments).
// value = Kb_ext[Ti*16 + (lane&15)][ks*32 + (lane>>4)*8 + j]
__global__ void prep_k2(const float* __restrict__ K, const float* __restrict__ rel,
                        u16* __restrict__ KF) {
  __shared__ float lds[16][65];
  const int b = blockIdx.y;
  const int Ti = blockIdx.x;           // 0..275
  const int tid = threadIdx.x;         // 128
  for (int i = tid; i < 1024; i += 128) {
    const int r = i >> 6, c = i & 63;
    const int t = Ti * 16 + r;
    float v = 0.f;
    if (t < S_LEN) v = K[((size_t)b * S_LEN + t) * DIM + c];
    else if (t - S_LEN < NPOS) v = rel[(size_t)(t - S_LEN) * DIM + c];
    lds[r][c] = v;
  }
  __syncthreads();
  const int ks = tid >> 6, lane = tid & 63;
  const int l15 = lane & 15, q4 = lane >> 4;
  s16x8 o;
#pragma unroll
  for (int j = 0; j < 8; ++j) o[j] = (short)f2bf(lds[l15][ks * 32 + q4 * 8 + j]);
  *reinterpret_cast<s16x8*>(KF + (((size_t)(b * NKT + Ti)) * 2 + ks) * 512 + lane * 8) = o;
}

// VF[b][T6][ks][dn][lane][j]: the exact s16x8 for the PV MFMA fragment.
// value = V[b][T6*64 + ks*32 + (lane>>4)*8 + j][dn*16 + (lane&15)]
__global__ void prep_v2(const float* __restrict__ V, u16* __restrict__ VF) {
  __shared__ float lds[64][65];
  const int b = blockIdx.y;
  const int T6 = blockIdx.x;           // 0..63
  const int tid = threadIdx.x;         // 256
  for (int i = tid; i < 4096; i += 256) {
    const int r = i >> 6, c = i & 63;
    lds[r][c] = V[((size_t)b * S_LEN + T6 * 64 + r) * DIM + c];
  }
  __syncthreads();
  const int dn = tid >> 6, lane = tid & 63;
  const int l15 = lane & 15, q4 = lane >> 4;
#pragma unroll
  for (int ks = 0; ks < 2; ++ks) {
    s16x8 o;
#pragma unroll
    for (int j = 0; j < 8; ++j) o[j] = (short)f2bf(lds[ks * 32 + q4 * 8 + j][dn * 16 + l15]);
    *reinterpret_cast<s16x8*>(
        VF + ((((size_t)(b * 64 + T6)) * 2 + ks) * 4 + dn) * 512 + lane * 8) = o;
  }
}

// 16 q-rows per block, 8 waves (512 thr); wave w owns cols [w*512,(w+1)*512).
// All K/V MFMA operands come from fragment-contiguous KF/VF (1KB coalesced
// wave-loads; 16x fewer L1 transactions than the strided Kb/Vt layout).
// Loop body/softmax/stores/epilogue identical to R11 (proven correct).
// Swapped-operand MFMAs keep q == l15 lane-local:
//   QK^T: mfma(kf, qf) -> D[t=q4*4+reg][q=l15]
//   PV:   mfma(vf, pf) -> D[d=dn*16+q4*4+reg][q=l15]
__launch_bounds__(512, 4)
__global__ void attn_main(const float* __restrict__ Q,
                          const u16* __restrict__ KF,
                          const u16* __restrict__ VF,
                          float* __restrict__ energy,
                          float* __restrict__ Zout) {
  __shared__ float uni[8448];          // phase1: qrel[16][260]; phase2: Zbuf[8][16][64]+m[128]+l[128]
  __shared__ u16 plds[8 * 16 * PSTR];  // 18432 B

  const int tid = threadIdx.x;
  const int lane = tid & 63;
  const int wid = tid >> 6;            // 0..7
  const int l15 = lane & 15, q4 = lane >> 4;
  const int bx = blockIdx.x;
  const int b = bx >> 8;
  const int s0 = (bx & 255) * 16;

  const u16* KFB = KF + (size_t)b * NKT * 2 * 512;
  const u16* VFB = VF + (size_t)b * 64 * 2 * 4 * 512;
  const int lane8 = lane * 8;

  // ---- Q B-fragments (row s0+l15) ----
  s16x8 qfrag[2];
  {
    const float* qp = Q + ((size_t)b * S_LEN + s0 + l15) * DIM + q4 * 8;
#pragma unroll
    for (int ks = 0; ks < 2; ++ks) {
      f32x4 a = *reinterpret_cast<const f32x4*>(qp + ks * 32);
      f32x4 c = *reinterpret_cast<const f32x4*>(qp + ks * 32 + 4);
      s16x8 f;
#pragma unroll
      for (int j = 0; j < 4; ++j) { f[j] = (short)f2bf(a[j]); f[4 + j] = (short)f2bf(c[j]); }
      qfrag[ks] = f;
    }
  }

  // ---- prologue: Q_rel[p][q] via mfma(rel_frag, q); waves 0..4 ----
  for (int pt = wid; pt < 5; pt += 8) {
    f32x4 acc[4] = {};
#pragma unroll
    for (int ks = 0; ks < 2; ++ks)
#pragma unroll
      for (int nf = 0; nf < 4; ++nf) {
        s16x8 kf = *reinterpret_cast<const s16x8*>(
            KFB + ((size_t)(256 + pt * 4 + nf) * 2 + ks) * 512 + lane8);
        acc[nf] = __builtin_amdgcn_mfma_f32_16x16x32_bf16(kf, qfrag[ks], acc[nf], 0, 0, 0);
      }
#pragma unroll
    for (int nf = 0; nf < 4; ++nf)
#pragma unroll
      for (int reg = 0; reg < 4; ++reg) {
        int p = pt * 64 + nf * 16 + q4 * 4 + reg;
        if (p < NPOS) uni[l15 * QREL_STR + p] = acc[nf][reg];
      }
  }
  __syncthreads();

  // per-row clamped-rel constants, pre-scaled by 1/8
  const float c8lo = uni[l15 * QREL_STR + 0] * 0.125f;
  const float c8hi = uni[l15 * QREL_STR + 256] * 0.125f;

  // ---- main loop: 8 t-tiles of 64 per wave, barrier-free ----
  const int qglob = s0 + l15;
  const int qoff = l15 * QREL_STR + RAD;
  u16* pw = plds + wid * 16 * PSTR;
  float* erow = energy + ((size_t)b * S_LEN + qglob) * S_LEN;

  float mprev = -INFINITY, lsum = 0.f;
  f32x4 zacc[4] = {};

  for (int it = 0; it < 8; ++it) {
    const int t0 = wid * 512 + it * 64;
    const int ti4 = t0 >> 4;           // K tile index base (4 per iter)
    const int t6 = t0 >> 6;            // V chunk index

    // QK^T from fragment-contiguous KF
    f32x4 acc[4] = {};
#pragma unroll
    for (int ks = 0; ks < 2; ++ks)
#pragma unroll
      for (int nf = 0; nf < 4; ++nf) {
        s16x8 kf = *reinterpret_cast<const s16x8*>(
            KFB + ((size_t)(ti4 + nf) * 2 + ks) * 512 + lane8);
        acc[nf] = __builtin_amdgcn_mfma_f32_16x16x32_bf16(kf, qfrag[ks], acc[nf], 0, 0, 0);
      }

    // V fragments issued early; latency hides under softmax
    s16x8 vf[2][4];
#pragma unroll
    for (int ks = 0; ks < 2; ++ks)
#pragma unroll
      for (int dn = 0; dn < 4; ++dn)
        vf[ks][dn] = *reinterpret_cast<const s16x8*>(
            VFB + (((size_t)t6 * 2 + ks) * 4 + dn) * 512 + lane8);

    // rel shift + scale (band-split), lane max
    float mloc = -INFINITY;
    if (t0 >= s0 + 143) {
#pragma unroll
      for (int nf = 0; nf < 4; ++nf)
#pragma unroll
        for (int reg = 0; reg < 4; ++reg) {
          float e = fmaf(acc[nf][reg], 0.125f, c8hi);
          acc[nf][reg] = e;
          mloc = fmaxf(mloc, e);
        }
    } else if (t0 <= s0 - 191) {
#pragma unroll
      for (int nf = 0; nf < 4; ++nf)
#pragma unroll
        for (int reg = 0; reg < 4; ++reg) {
          float e = fmaf(acc[nf][reg], 0.125f, c8lo);
          acc[nf][reg] = e;
          mloc = fmaxf(mloc, e);
        }
    } else {
#pragma unroll
      for (int nf = 0; nf < 4; ++nf) {
        const int tb = t0 + nf * 16 + q4 * 4;
#pragma unroll
        for (int reg = 0; reg < 4; ++reg) {
          int p = tb + reg - qglob;
          p = (p < -RAD) ? -RAD : (p > RAD ? RAD : p);
          float e = (acc[nf][reg] + uni[qoff + p]) * 0.125f;
          acc[nf][reg] = e;
          mloc = fmaxf(mloc, e);
        }
      }
    }

    // energy store, direct from regs (R6/R9: stores not the bottleneck)
#pragma unroll
    for (int nf = 0; nf < 4; ++nf)
      __builtin_nontemporal_store(
          acc[nf], reinterpret_cast<f32x4*>(erow + t0 + nf * 16 + q4 * 4));

    // online softmax; skip rescale when max didn't grow
    if (__all(mloc <= mprev)) {
    } else {
      mloc = fmaxf(mloc, __shfl_xor(mloc, 16));
      mloc = fmaxf(mloc, __shfl_xor(mloc, 32));
      const float mn = fmaxf(mprev, mloc);
      const float alpha = __expf(mprev - mn);
      mprev = mn;
      lsum *= alpha;
#pragma unroll
      for (int dn = 0; dn < 4; ++dn) zacc[dn] *= alpha;
    }

    float rs = 0.f;
#pragma unroll
    for (int nf = 0; nf < 4; ++nf) {
      float p0 = __expf(acc[nf][0] - mprev);
      float p1 = __expf(acc[nf][1] - mprev);
      float p2 = __expf(acc[nf][2] - mprev);
      float p3 = __expf(acc[nf][3] - mprev);
      rs += (p0 + p1) + (p2 + p3);
      union { u32 w[2]; s16x4 v; } pk;
      asm("v_cvt_pk_bf16_f32 %0, %1, %2" : "=v"(pk.w[0]) : "v"(p0), "v"(p1));
      asm("v_cvt_pk_bf16_f32 %0, %1, %2" : "=v"(pk.w[1]) : "v"(p2), "v"(p3));
      *reinterpret_cast<s16x4*>(pw + l15 * PSTR + nf * 16 + q4 * 4) = pk.v;
    }
    rs += __shfl_xor(rs, 16);
    rs += __shfl_xor(rs, 32);
    lsum += rs;

    // PV: mfma(vf, pf) -> zacc[dn] holds Z[d=dn*16+q4*4+reg][q=l15]
#pragma unroll
    for (int ks = 0; ks < 2; ++ks) {
      s16x8 pf = *reinterpret_cast<const s16x8*>(pw + l15 * PSTR + ks * 32 + q4 * 8);
#pragma unroll
      for (int dn = 0; dn < 4; ++dn)
        zacc[dn] = __builtin_amdgcn_mfma_f32_16x16x32_bf16(vf[ks][dn], pf, zacc[dn], 0, 0, 0);
    }
  }

  // ---- cross-wave combine (reuse uni: Zbuf, m, l) ----
  __syncthreads();
#pragma unroll
  for (int dn = 0; dn < 4; ++dn)
    *reinterpret_cast<f32x4*>(&uni[(wid * 16 + l15) * 64 + dn * 16 + q4 * 4]) = zacc[dn];
  if (q4 == 0) {
    uni[8192 + wid * 16 + l15] = mprev;
    uni[8320 + wid * 16 + l15] = lsum;
  }
  __syncthreads();

  {
    const int r0 = tid >> 6, d = tid & 63;
#pragma unroll
    for (int rr = 0; rr < 2; ++rr) {
      const int r = rr * 8 + r0;
      float mf = -INFINITY;
#pragma unroll
      for (int w = 0; w < 8; ++w) mf = fmaxf(mf, uni[8192 + w * 16 + r]);
      float lf = 0.f, z = 0.f;
#pragma unroll
      for (int w = 0; w < 8; ++w) {
        const float sc = __expf(uni[8192 + w * 16 + r] - mf);
        lf += uni[8320 + w * 16 + r] * sc;
        z  += uni[(w * 16 + r) * 64 + d] * sc;
      }
      Zout[((size_t)b * S_LEN + s0 + r) * DIM + d] = z / lf;
    }
  }
}

extern "C" void kernel_launch(void* const* d_in, const int* in_sizes, int n_in,
                              void* d_out, int out_size, void* d_ws, size_t ws_size,
                              hipStream_t stream) {
  const float* Q   = (const float*)d_in[0];
  const float* K   = (const float*)d_in[1];
  const float* V   = (const float*)d_in[2];
  const float* rel = (const float*)d_in[3];
  // d_in[4] = segment_ids (unused, segmented=False)

  u16* KF = (u16*)d_ws;                                   // [B][276][2][512] bf16 (1.1 MB)
  u16* VF = KF + (size_t)BATCH * NKT * 2 * 512;           // [B][64][2][4][512] bf16 (1 MB)

  float* energy = (float*)d_out;                          // [B][S][S]
  float* Zout   = energy + (size_t)BATCH * S_LEN * S_LEN; // [B][S][64]

  prep_k2<<<dim3(NKT, BATCH), 128, 0, stream>>>(K, rel, KF);
  prep_v2<<<dim3(S_LEN / 64, BATCH), 256, 0, stream>>>(V, VF);
  attn_main<<<dim3(BATCH * (S_LEN / 16)), 512, 0, stream>>>(Q, KF, VF, energy, Zout);
}